// Round 2
// baseline (44.391 us; speedup 1.0000x reference)
//
#include <hip/hip_runtime.h>
#include <stdint.h>
#include <float.h>

typedef unsigned long long u64;

#define KK 64
#define NN 128
#define NPAIR 2016
#define NCAND 2081   // 1 + 64 + 2016

__global__ __launch_bounds__(256) void osd_kernel(
    const float* __restrict__ llr_g,
    const float* __restrict__ gm_g,
    float* __restrict__ out_g)
{
    const int b    = blockIdx.x;
    const int tid  = threadIdx.x;
    const int lane = tid & 63;
    const int wave = tid >> 6;

    __shared__ float llr_ch[NN];     // clipped llr, original column order
    __shared__ float aabs[NN];       // |llr_ch|
    __shared__ int   idx_sort[NN];   // reliability permutation (desc |llr|, stable)
    __shared__ u64   gorig[KK][2];   // gm bits, original column order
    __shared__ u64   g[KK][2];       // gm bits, sorted columns (then eliminated)
    __shared__ int   piv[KK];
    __shared__ int   keyArr[NN];
    __shared__ int   mrb[NN];        // MRB column permutation (in sorted-col space)
    __shared__ int   idx_full[NN];   // final order -> original column index
    __shared__ float w[NN];          // |llr| in final order
    __shared__ u64   R[KK][2];       // gm_mrb rows as bitsets
    __shared__ u64   cw[2];          // base codeword c (later: winner)
    __shared__ u64   hb[2];          // hard-decision bits (final order)
    __shared__ u64   baseMis[2];     // c XOR hard-decision
    __shared__ float lut[16][256];   // per-byte subset sums of w
    __shared__ unsigned short pairTab[NPAIR];
    __shared__ float wS[4];
    __shared__ int   wId[4];

    // ---- 1. load + clip llr ----
    if (tid < NN) {
        float v = llr_g[b * NN + tid];
        v = fminf(fmaxf(v, -100.0f), 100.0f);
        llr_ch[tid] = v;
        aabs[tid]   = fabsf(v);
    }
    // ---- 2. stage gm as bitsets via ballot (coalesced) ----
    for (int it = 0; it < 32; ++it) {
        int widx = wave + 4 * it;                 // 0..127 half-row index
        float v  = gm_g[widx * 64 + lane];
        u64 m    = __ballot(v != 0.0f);
        if (lane == 0) gorig[widx >> 1][widx & 1] = m;
    }
    __syncthreads();

    // ---- 3. stable rank sort by descending |llr| ----
    if (tid < NN) {
        float ai = aabs[tid];
        int r = 0;
        for (int j = 0; j < NN; ++j) {
            float aj = aabs[j];
            r += (aj > ai) || (aj == ai && j < tid);
        }
        idx_sort[r] = tid;
    }
    __syncthreads();

    // ---- 4. permute gm columns into reliability order ----
    if (tid < KK) {
        u64 o0 = gorig[tid][0], o1 = gorig[tid][1];
        u64 w0 = 0, w1 = 0;
        for (int j = 0; j < 64; ++j) {
            int c = idx_sort[j];
            u64 bit = (c < 64) ? ((o0 >> c) & 1ull) : ((o1 >> (c - 64)) & 1ull);
            w0 |= bit << j;
        }
        for (int j = 64; j < NN; ++j) {
            int c = idx_sort[j];
            u64 bit = (c < 64) ? ((o0 >> c) & 1ull) : ((o1 >> (c - 64)) & 1ull);
            w1 |= bit << (j - 64);
        }
        g[tid][0] = w0; g[tid][1] = w1;
    }
    __syncthreads();

    // ---- 5. GF(2) Gaussian elimination (matches jax: pivot = first set bit, 0 if none) ----
    for (int ic = 0; ic < KK; ++ic) {
        u64 r0 = g[ic][0], r1 = g[ic][1];
        int p = r0 ? (__ffsll(r0) - 1) : (r1 ? (64 + __ffsll(r1) - 1) : 0);
        if (tid == 0) piv[ic] = p;
        if (tid < KK && tid != ic) {
            u64 bit = (p < 64) ? ((g[tid][0] >> p) & 1ull)
                               : ((g[tid][1] >> (p - 64)) & 1ull);
            if (bit) { g[tid][0] ^= r0; g[tid][1] ^= r1; }
        }
        __syncthreads();
    }

    // ---- 6. parity columns: key = col + 128*count(pivots==col); take 64 smallest ----
    if (tid < NN) {
        int cnt = 0;
        for (int m = 0; m < KK; ++m) cnt += (piv[m] == tid);
        keyArr[tid] = tid + NN * cnt;
    }
    __syncthreads();
    if (tid < KK) mrb[tid] = piv[tid];
    if (tid < NN) {
        int kk = keyArr[tid];
        int r = 0;
        for (int j = 0; j < NN; ++j) r += (keyArr[j] < kk);
        if (r < 64) mrb[KK + r] = tid;
    }
    __syncthreads();

    // ---- 7. final-order llr data ----
    if (tid < NN) {
        int oc = idx_sort[mrb[tid]];
        idx_full[tid] = oc;
        w[tid] = fabsf(llr_ch[oc]);
    }
    __syncthreads();
    if (wave < 2) {
        float v = llr_ch[idx_full[wave * 64 + lane]];
        u64 m = __ballot(v < 0.0f);
        if (lane == 0) hb[wave] = m;
    }

    // ---- 8. gm_mrb rows as bitsets ----
    if (tid < KK) {
        u64 g0 = g[tid][0], g1 = g[tid][1];
        u64 w0 = 0, w1 = 0;
        for (int j = 0; j < 64; ++j) {
            int c = mrb[j];
            u64 bit = (c < 64) ? ((g0 >> c) & 1ull) : ((g1 >> (c - 64)) & 1ull);
            w0 |= bit << j;
        }
        for (int j = 64; j < NN; ++j) {
            int c = mrb[j];
            u64 bit = (c < 64) ? ((g0 >> c) & 1ull) : ((g1 >> (c - 64)) & 1ull);
            w1 |= bit << (j - 64);
        }
        R[tid][0] = w0; R[tid][1] = w1;
    }
    __syncthreads();   // also covers hb writes above

    // ---- 9. base codeword c = XOR of rows where u_hd==1 ----
    if (wave == 0) {
        u64 hbit = (hb[0] >> lane) & 1ull;
        u64 v0 = hbit ? R[lane][0] : 0ull;
        u64 v1 = hbit ? R[lane][1] : 0ull;
        for (int off = 32; off; off >>= 1) {
            v0 ^= __shfl_xor(v0, off);
            v1 ^= __shfl_xor(v1, off);
        }
        if (lane == 0) {
            cw[0] = v0; cw[1] = v1;
            baseMis[0] = v0 ^ hb[0];
            baseMis[1] = v1 ^ hb[1];
        }
    }

    // ---- 10. byte-subset-sum LUT + pair table ----
    for (int e = tid; e < 4096; e += 256) {
        int p = e >> 8, m = e & 255;
        float s = 0.0f;
        #pragma unroll
        for (int bp = 0; bp < 8; ++bp)
            if (m & (1 << bp)) s += w[p * 8 + bp];
        lut[p][m] = s;
    }
    if (tid < KK) {
        int i = tid;
        int off = 63 * i - (i * (i - 1)) / 2;
        for (int j = i + 1; j < 64; ++j)
            pairTab[off + (j - i - 1)] = (unsigned short)((i << 8) | j);
    }
    __syncthreads();

    // ---- 11. candidate search ----
    // d = const + (1/n) * sum_{matched} |llr|  ==>  argmin d == argmax S where
    // S = sum_{mismatched} |llr|.  Global lexicographic (max S, min id) over
    // id order {0=base, 1..64 = t1, 65..2080 = t2} reproduces the reference's
    // per-round first-argmin + strict-improvement semantics.
    float bestS = -FLT_MAX;
    int bestId  = 0x7fffffff;
    u64 b0 = baseMis[0], b1 = baseMis[1];
    for (int id = tid; id < NCAND; id += 256) {
        u64 m0 = b0, m1 = b1;
        if (id >= 65) {
            int pr = pairTab[id - 65];
            int i = pr >> 8, j = pr & 255;
            m0 ^= R[i][0] ^ R[j][0];
            m1 ^= R[i][1] ^ R[j][1];
        } else if (id >= 1) {
            int i = id - 1;
            m0 ^= R[i][0];
            m1 ^= R[i][1];
        }
        float s = lut[0][(int)(m0 & 255)]
                + lut[1][(int)((m0 >> 8) & 255)]
                + lut[2][(int)((m0 >> 16) & 255)]
                + lut[3][(int)((m0 >> 24) & 255)]
                + lut[4][(int)((m0 >> 32) & 255)]
                + lut[5][(int)((m0 >> 40) & 255)]
                + lut[6][(int)((m0 >> 48) & 255)]
                + lut[7][(int)((m0 >> 56) & 255)]
                + lut[8][(int)(m1 & 255)]
                + lut[9][(int)((m1 >> 8) & 255)]
                + lut[10][(int)((m1 >> 16) & 255)]
                + lut[11][(int)((m1 >> 24) & 255)]
                + lut[12][(int)((m1 >> 32) & 255)]
                + lut[13][(int)((m1 >> 40) & 255)]
                + lut[14][(int)((m1 >> 48) & 255)]
                + lut[15][(int)((m1 >> 56) & 255)];
        // within-thread ids are increasing, so '>' keeps the earliest id on ties
        if (s > bestS) { bestS = s; bestId = id; }
    }
    // wave-level reduce (max S, tie -> min id)
    for (int off = 32; off; off >>= 1) {
        float os = __shfl_xor(bestS, off);
        int  oid = __shfl_xor(bestId, off);
        if (os > bestS || (os == bestS && oid < bestId)) { bestS = os; bestId = oid; }
    }
    if (lane == 0) { wS[wave] = bestS; wId[wave] = bestId; }
    __syncthreads();
    if (tid == 0) {
        for (int wv = 1; wv < 4; ++wv)
            if (wS[wv] > bestS || (wS[wv] == bestS && wId[wv] < bestId)) {
                bestS = wS[wv]; bestId = wId[wv];
            }
        u64 c0 = cw[0], c1 = cw[1];
        if (bestId >= 65) {
            int pr = pairTab[bestId - 65];
            int i = pr >> 8, j = pr & 255;
            c0 ^= R[i][0] ^ R[j][0];
            c1 ^= R[i][1] ^ R[j][1];
        } else if (bestId >= 1) {
            int i = bestId - 1;
            c0 ^= R[i][0];
            c1 ^= R[i][1];
        }
        cw[0] = c0; cw[1] = c1;
    }
    __syncthreads();

    // ---- 12. scatter winner back to original column order ----
    if (tid < NN) {
        u64 bit = (tid < 64) ? ((cw[0] >> tid) & 1ull)
                             : ((cw[1] >> (tid - 64)) & 1ull);
        out_g[b * NN + idx_full[tid]] = bit ? 1.0f : 0.0f;
    }
}

extern "C" void kernel_launch(void* const* d_in, const int* in_sizes, int n_in,
                              void* d_out, int out_size, void* d_ws, size_t ws_size,
                              hipStream_t stream) {
    const float* llr = (const float*)d_in[0];
    const float* gm  = (const float*)d_in[1];
    float* out       = (float*)d_out;
    int bs = in_sizes[0] / NN;   // 128
    osd_kernel<<<bs, 256, 0, stream>>>(llr, gm, out);
}